// Round 7
// baseline (264.745 us; speedup 1.0000x reference)
//
#include <hip/hip_runtime.h>

#define LVLS  16
#define TSZ   524288u          // 2^19
#define TMASK (TSZ - 1u)
#define PRIME 2654435761u

// floor(16 * g^l), g = 128^(1/15) — matches np float64 floor then f32 cast
__constant__ float RES[LVLS] = {16.f, 22.f, 30.f, 42.f, 58.f, 80.f, 111.f, 153.f,
                                212.f, 294.f, 406.f, 561.f, 776.f, 1072.f, 1482.f, 2048.f};

// Dense-pair geometry for levels 4..7: dp[iy*res + ix] = (v[ix],v[ix+1]) at
// vertex row iy. iy in [0,res], ix in [0,res-1] -> (res+1)*res entries.
__constant__ int PRES[4] = {58, 80, 111, 153};
__constant__ int POFF[4] = {0, 3422, 9902, 22334};   // float4 units
#define PAIR_TOTAL 45896                             // * 16 B = 734 KB

typedef __bf16 bf16x8 __attribute__((ext_vector_type(8)));
typedef float  f32x4  __attribute__((ext_vector_type(4)));

union Frag {
    uint4          q;
    unsigned       u[4];
    unsigned short s[8];
    bf16x8         v;
};

static __device__ __forceinline__ unsigned short f2bf(float f) {
    unsigned u = __float_as_uint(f);
    u += 0x7FFFu + ((u >> 16) & 1u);          // RNE; inputs finite, non-NaN
    return (unsigned short)(u >> 16);
}
static __device__ __forceinline__ unsigned pack2(float a, float b) {
    return (unsigned)f2bf(a) | ((unsigned)f2bf(b) << 16);
}
// order LDS phases without cross-wave barriers (per-wave scratch only)
static __device__ __forceinline__ void lds_fence() {
    asm volatile("s_waitcnt lgkmcnt(0)" ::: "memory");
}

// Shared per-level encode math (identical FP sequence everywhere).
static __device__ __forceinline__ unsigned encode_level(
    const float2 xy, const float res, const float* __restrict__ tbf)
{
    const float sx = xy.x * res, sy = xy.y * res;
    const float fx = floorf(sx),  fy = floorf(sy);
    const float ux = sx - fx,     uy = sy - fy;
    const unsigned ix = (unsigned)(int)fx, iy = (unsigned)(int)fy;
    const unsigned hy0 = iy * PRIME, hy1 = (iy + 1u) * PRIME;
    const unsigned i00 = (ix ^ hy0) & TMASK;
    const unsigned i01 = (ix ^ hy1) & TMASK;
    float2 f00, f10, f01, f11;
    if (!(ix & 1u)) {
        // ix even -> i10 = i00^1, i11 = i01^1: each y-row's two corners are an
        // aligned 16 B pair -> one dwordx4 each (2 transactions, no extra bytes).
        const f32x4 a = *(const f32x4*)(tbf + 2u * (i00 & ~1u));
        const f32x4 b = *(const f32x4*)(tbf + 2u * (i01 & ~1u));
        const bool s0 = (i00 & 1u) != 0u;
        const bool s1 = (i01 & 1u) != 0u;
        f00 = s0 ? make_float2(a[2], a[3]) : make_float2(a[0], a[1]);
        f10 = s0 ? make_float2(a[0], a[1]) : make_float2(a[2], a[3]);
        f01 = s1 ? make_float2(b[2], b[3]) : make_float2(b[0], b[1]);
        f11 = s1 ? make_float2(b[0], b[1]) : make_float2(b[2], b[3]);
    } else {
        const unsigned i10 = ((ix + 1u) ^ hy0) & TMASK;
        const unsigned i11 = ((ix + 1u) ^ hy1) & TMASK;
        const float2* tb2 = (const float2*)tbf;
        f00 = tb2[i00]; f10 = tb2[i10];
        f01 = tb2[i01]; f11 = tb2[i11];
    }
    const float w00 = (1.f - ux) * (1.f - uy);
    const float w10 = ux * (1.f - uy);
    const float w01 = (1.f - ux) * uy;
    const float w11 = ux * uy;
    const float e0 = w00*f00.x + w10*f10.x + w01*f01.x + w11*f11.x;
    const float e1 = w00*f00.y + w10*f10.y + w01*f01.y + w11*f11.y;
    return pack2(e0, e1);
}

// Dense (de-hashed) coarse-table geometry, levels 0..3 (LDS-staged in K2).
// W = res+1 vertices per side: {17,23,31,43} -> 289,529,961,1849 entries,
// offsets {0,289,818,1779}, total 3628 entries = 29 KB of float2.
#define DENSE_TOTAL 3628

// ============ K0a: de-hash L0-3 into dense [iy][ix] layout ============
__global__ __launch_bounds__(256) void ngp_dehash(
    const float* __restrict__ tables, float2* __restrict__ dense)
{
    const int e = blockIdx.x * 256 + (int)threadIdx.x;
    if (e >= DENSE_TOTAL) return;
    int l, base;
    if      (e >= 1779) { l = 3; base = 1779; }
    else if (e >=  818) { l = 2; base =  818; }
    else if (e >=  289) { l = 1; base =  289; }
    else                { l = 0; base =    0; }
    const int Wd = (l == 0) ? 17 : (l == 1) ? 23 : (l == 2) ? 31 : 43;
    const int r  = e - base;
    const unsigned iy = (unsigned)(r / Wd), ix = (unsigned)(r % Wd);
    const unsigned h = (ix ^ (iy * PRIME)) & TMASK;
    dense[e] = ((const float2*)(tables + (size_t)l * (TSZ * 2u)))[h];
}

// ============ K0b: de-hash L4-7 into dense PAIR layout ============
// dp[off + iy*res + ix] = (v[iy][ix], v[iy][ix+1]) -> every point-level in K2
// becomes exactly 2 aligned dwordx4 loads, regardless of ix parity.
// Values are exact copies -> numerics unchanged.
__global__ __launch_bounds__(256) void ngp_dehash_pair(
    const float* __restrict__ tables, f32x4* __restrict__ pairs)
{
    const int li = blockIdx.y;                 // 0..3 -> level 4+li
    const int res = PRES[li];
    const int cnt = (res + 1) * res;
    const int e = blockIdx.x * 256 + (int)threadIdx.x;
    if (e >= cnt) return;
    const unsigned iy = (unsigned)(e / res), ix = (unsigned)(e % res);
    const unsigned hy = iy * PRIME;
    const float2* tb2 = (const float2*)(tables + (size_t)(4 + li) * (TSZ * 2u));
    const float2 v0 = tb2[(ix ^ hy) & TMASK];
    const float2 v1 = tb2[((ix + 1u) ^ hy) & TMASK];
    f32x4 p; p[0] = v0.x; p[1] = v0.y; p[2] = v1.x; p[3] = v1.y;
    pairs[POFF[li] + e] = p;
}

// ============ K1: fine levels 8..15, XCD-affine, 2 points/thread ============
// blockIdx%8 == XCD id (round-robin dispatch): level 8+k runs only on XCD k,
// its table stays L2-resident. 2 points/thread doubles per-lane loads in
// flight (~6 vs 3) — discriminates wave-latency-limited (gains) from
// MSHR-walled (no change) at identical transaction/byte counts.
__global__ __launch_bounds__(256) void ngp_encode_fine(
    const float* __restrict__ x, const float* __restrict__ tables,
    unsigned* __restrict__ feat, int N)
{
    const int g = blockIdx.x;
    const int r = g & 7;              // XCD id
    const int l = 8 + r;              // fine level pinned to this XCD
    const int n0 = (g >> 3) * 512 + (int)threadIdx.x;
    const int n1 = n0 + 256;
    const float* tbf = tables + (size_t)l * (TSZ * 2u);
    const float res = RES[l];
    float2 xy0, xy1;
    if (n0 < N) xy0 = ((const float2*)x)[n0];
    if (n1 < N) xy1 = ((const float2*)x)[n1];
    unsigned p0 = 0, p1 = 0;
    if (n0 < N) p0 = encode_level(xy0, res, tbf);
    if (n1 < N) p1 = encode_level(xy1, res, tbf);
    if (n0 < N) feat[(size_t)r * N + n0] = p0;    // coalesced
    if (n1 < N) feat[(size_t)r * N + n1] = p1;
}

// ============ K2: coarse levels 0..7 + feat + MLP ============
// L0-3 from LDS-staged dense table (no TA transactions); L4-7 from global
// dense-pair arrays (735 KB total -> L2-resident on every XCD; 2 aligned
// dwordx4 per point-level, branchless). K2 no longer touches hashed tables.
// Block = 512 threads = 8 waves = 512 points; each wave runs the MFMA MLP on
// its 64 points (4 tiles of 16). A-frag quads 0-1 (levels 0-7) come from LDS
// sfeat; quads 2-3 (levels 8-15) stream coalesced from K1's feat.
//
// LDS phases (region after sfeat is time-shared):
//   phase A (staging+encode+preload): sB0 4K | sB1 8K | sdense 29K  = 41.3 KB
//   phase B (MLP):                    hscr 18.4 KB (aliases region base)
// syncs: [stage sB+sdense] S1 [encode] S2 [preload B] S3 [MLP].
//
// launch_bounds min-waves/EU MUST stay at 4 (round-2: asking 6 spilled the
// persistent B-frags to scratch, WRITE_SIZE 12->197 MB, 183->330 us).
//
// Layouts (m89/m120-verified): A[m=lane&15][k=quad*8+j], B[k=quad*8+j][n=lane&15],
// C/D col=lane&15 row=quad*4+reg.
#define CLVL 8
#define SFEAT_BYTES (8 * CLVL * 64 * 4)            // 16384
#define SB0_BYTES   (4 * 64 * 16)                  // 4096
#define SB1_BYTES   (8 * 64 * 16)                  // 8192
#define SDENSE_BYTES (DENSE_TOTAL * 8)             // 29024
#define REGION_BYTES (SB0_BYTES + SB1_BYTES + SDENSE_BYTES)   // 41312

__global__ __launch_bounds__(512, 4) void ngp_fused(
    const float* __restrict__ x,
    const float2* __restrict__ dense_g,
    const f32x4* __restrict__ pairs,
    const unsigned* __restrict__ feat,
    const float* __restrict__ W0, const float* __restrict__ b0,
    const float* __restrict__ W1, const float* __restrict__ b1,
    const float* __restrict__ W2, const float* __restrict__ b2,
    float* __restrict__ out, int N)
{
    __shared__ __align__(16) unsigned char smem[SFEAT_BYTES + REGION_BYTES];  // 57.7 KB
    // sfeat[w][lvl][col]: col XOR-swizzled by (lvl>>2)&1 so the A0 read
    // (2 coarse quads at same 16-col window) spreads across banks.
    unsigned* sfeat = (unsigned*)smem;                                   // [8][8][64]
    uint4*    sB0   = (uint4*)(smem + SFEAT_BYTES);                      // [4*64]
    uint4*    sB1   = (uint4*)(smem + SFEAT_BYTES + SB0_BYTES);          // [8*64]
    float2*   sdense = (float2*)(smem + SFEAT_BYTES + SB0_BYTES + SB1_BYTES);
    unsigned short (*hscr)[16][72] =
        (unsigned short (*)[16][72])(smem + SFEAT_BYTES);                // phase-B alias

    const int tid  = threadIdx.x;
    const int lane = tid & 63;
    const int w    = tid >> 6;       // wave 0..7
    const int c    = lane & 15;
    const int quad = lane >> 4;

    // ---- stage B fragments (bf16, B-operand layout) + dense tables ----
    {
        const int f = w;             // 0..7
        if (f < 4) {
            Frag t0;
            #pragma unroll
            for (int j = 0; j < 8; ++j)
                t0.s[j] = f2bf(W0[(quad * 8 + j) * 64 + f * 16 + c]);
            sB0[f * 64 + lane] = t0.q;
        }
        {
            const int kt = f >> 2, tt = f & 3;
            Frag t1;
            #pragma unroll
            for (int j = 0; j < 8; ++j)
                t1.s[j] = f2bf(W1[(kt * 32 + quad * 8 + j) * 64 + tt * 16 + c]);
            sB1[f * 64 + lane] = t1.q;
        }
        for (int e = tid; e < DENSE_TOTAL; e += 512)
            sdense[e] = dense_g[e];            // coalesced, L2/LLC-hit
    }
    __syncthreads();   // S1: sdense visible

    // ---- encode coarse levels 0..7 for this thread's point -> sfeat ----
    const int n = blockIdx.x * 512 + tid;
    if (n < N) {
        const float2 xy = ((const float2*)x)[n];
        // L0-3: dense LDS lookup (no hash, no vector-memory transactions)
        #pragma unroll
        for (int l = 0; l < 4; ++l) {
            const int off = (l == 0) ? 0 : (l == 1) ? 289 : (l == 2) ? 818 : 1779;
            const int Wd  = (l == 0) ? 17 : (l == 1) ? 23 : (l == 2) ? 31 : 43;
            const float res = RES[l];
            const float sx = xy.x * res, sy = xy.y * res;
            const float fx = floorf(sx),  fy = floorf(sy);
            const float ux = sx - fx,     uy = sy - fy;
            const int ix = (int)fx, iy = (int)fy;
            const int b = off + iy * Wd + ix;
            const float2 f00 = sdense[b],      f10 = sdense[b + 1];
            const float2 f01 = sdense[b + Wd], f11 = sdense[b + Wd + 1];
            const float w00 = (1.f - ux) * (1.f - uy);
            const float w10 = ux * (1.f - uy);
            const float w01 = (1.f - ux) * uy;
            const float w11 = ux * uy;
            const float e0 = w00*f00.x + w10*f10.x + w01*f01.x + w11*f11.x;
            const float e1 = w00*f00.y + w10*f10.y + w01*f01.y + w11*f11.y;
            sfeat[(w * CLVL + l) * 64 + (lane ^ (((l >> 2) & 1) << 4))] = pack2(e0, e1);
        }
        // L4-7: dense-pair gathers (2 aligned dwordx4 each, branchless)
        #pragma unroll
        for (int li = 0; li < 4; ++li) {
            const int l = 4 + li;
            const float res = RES[l];
            const int Wp = PRES[li];
            const float sx = xy.x * res, sy = xy.y * res;
            const float fx = floorf(sx),  fy = floorf(sy);
            const float ux = sx - fx,     uy = sy - fy;
            const int ix = (int)fx, iy = (int)fy;
            const int b = POFF[li] + iy * Wp + ix;
            const f32x4 r0 = pairs[b];          // (f00.x f00.y f10.x f10.y)
            const f32x4 r1 = pairs[b + Wp];     // (f01.x f01.y f11.x f11.y)
            const float w00 = (1.f - ux) * (1.f - uy);
            const float w10 = ux * (1.f - uy);
            const float w01 = (1.f - ux) * uy;
            const float w11 = ux * uy;
            const float e0 = w00*r0[0] + w10*r0[2] + w01*r1[0] + w11*r1[2];
            const float e1 = w00*r0[1] + w10*r0[3] + w01*r1[1] + w11*r1[3];
            sfeat[(w * CLVL + l) * 64 + (lane ^ (((l >> 2) & 1) << 4))] = pack2(e0, e1);
        }
    }
    __syncthreads();   // S2: sfeat ready; sdense dead after this point

    // ---- preload B frags + biases to registers ----
    Frag B0f[4], B1f[8], B2f[2];
    #pragma unroll
    for (int t = 0; t < 4; ++t) B0f[t].q = sB0[t * 64 + lane];
    #pragma unroll
    for (int f = 0; f < 8; ++f) B1f[f].q = sB1[f * 64 + lane];
    #pragma unroll
    for (int f = 0; f < 2; ++f) {
        #pragma unroll
        for (int j = 0; j < 8; ++j) {
            const float v = (c < 3) ? W2[(f * 32 + quad * 8 + j) * 3 + c] : 0.f;
            B2f[f].s[j] = f2bf(v);
        }
    }

    float bias0[4], bias1[4];
    #pragma unroll
    for (int t = 0; t < 4; ++t) { bias0[t] = b0[t * 16 + c]; bias1[t] = b1[t * 16 + c]; }
    const float bias2 = (c < 3) ? b2[c] : 0.f;

    // S3: all waves done reading sB0/sB1 -> hscr may overwrite the region
    __syncthreads();

    // ---- 4 tiles of 16 points per wave ----
    #pragma unroll 1
    for (int it = 0; it < 4; ++it) {
        const int n0 = blockIdx.x * 512 + w * 64 + it * 16;

        // A0: dword i = levels quad*4+i -> k = quad*8+2i,2i+1
        // quads 0-1: coarse from sfeat (read swizzle ((quad*4+i)>>2)&1 == quad);
        // quads 2-3: fine from feat (coalesced 16x4B per (quad,i) group).
        Frag a0;
        if (quad < 2) {
            #pragma unroll
            for (int i = 0; i < 4; ++i)
                a0.u[i] = sfeat[(w * CLVL + quad * 4 + i) * 64 + ((it * 16 + c) ^ (quad << 4))];
        } else {
            #pragma unroll
            for (int i = 0; i < 4; ++i)
                a0.u[i] = feat[(size_t)((quad - 2) * 4 + i) * N + n0 + c];
        }

        f32x4 acc0[4];
        #pragma unroll
        for (int t = 0; t < 4; ++t) {
            f32x4 cin = {bias0[t], bias0[t], bias0[t], bias0[t]};
            acc0[t] = __builtin_amdgcn_mfma_f32_16x16x32_bf16(a0.v, B0f[t].v, cin, 0, 0, 0);
        }

        // h1 = relu(acc0) -> LDS scratch [point][neuron]
        lds_fence();
        #pragma unroll
        for (int t = 0; t < 4; ++t)
            #pragma unroll
            for (int rr = 0; rr < 4; ++rr)
                hscr[w][quad * 4 + rr][t * 16 + c] = f2bf(fmaxf(acc0[t][rr], 0.f));

        lds_fence();
        Frag a1[2];
        #pragma unroll
        for (int kt = 0; kt < 2; ++kt)
            a1[kt].q = *(const uint4*)&hscr[w][c][kt * 32 + quad * 8];

        f32x4 acc1[4];
        #pragma unroll
        for (int t = 0; t < 4; ++t) {
            f32x4 cin = {bias1[t], bias1[t], bias1[t], bias1[t]};
            cin = __builtin_amdgcn_mfma_f32_16x16x32_bf16(a1[0].v, B1f[t].v, cin, 0, 0, 0);
            acc1[t] = __builtin_amdgcn_mfma_f32_16x16x32_bf16(a1[1].v, B1f[4 + t].v, cin, 0, 0, 0);
        }

        // h2 = relu(acc1) -> LDS scratch
        lds_fence();
        #pragma unroll
        for (int t = 0; t < 4; ++t)
            #pragma unroll
            for (int rr = 0; rr < 4; ++rr)
                hscr[w][quad * 4 + rr][t * 16 + c] = f2bf(fmaxf(acc1[t][rr], 0.f));

        lds_fence();
        Frag a2[2];
        #pragma unroll
        for (int kt = 0; kt < 2; ++kt)
            a2[kt].q = *(const uint4*)&hscr[w][c][kt * 32 + quad * 8];

        f32x4 cin2 = {bias2, bias2, bias2, bias2};
        cin2 = __builtin_amdgcn_mfma_f32_16x16x32_bf16(a2[0].v, B2f[0].v, cin2, 0, 0, 0);
        f32x4 acc2 = __builtin_amdgcn_mfma_f32_16x16x32_bf16(a2[1].v, B2f[1].v, cin2, 0, 0, 0);

        // sigmoid + store: lane col c<3, rows quad*4+rr
        if (c < 3) {
            #pragma unroll
            for (int rr = 0; rr < 4; ++rr) {
                if (n0 + quad * 4 + rr < N) {
                    const float s = 1.f / (1.f + __expf(-acc2[rr]));
                    out[(size_t)(n0 + quad * 4 + rr) * 3 + c] = s;
                }
            }
        }
    }
}

extern "C" void kernel_launch(void* const* d_in, const int* in_sizes, int n_in,
                              void* d_out, int out_size, void* d_ws, size_t ws_size,
                              hipStream_t stream) {
    const float* x      = (const float*)d_in[0];
    const float* tables = (const float*)d_in[1];
    const float* W0     = (const float*)d_in[2];
    const float* b0     = (const float*)d_in[3];
    const float* W1     = (const float*)d_in[4];
    const float* b1     = (const float*)d_in[5];
    const float* W2     = (const float*)d_in[6];
    const float* b2     = (const float*)d_in[7];
    float* out = (float*)d_out;
    (void)ws_size; (void)n_in; (void)out_size;

    const int N  = in_sizes[0] / 2;
    unsigned* feat  = (unsigned*)d_ws;                                   // 8*N*4 = 32 MB
    float2*   dense = (float2*)((char*)d_ws + (size_t)8 * N * 4);        // +29 KB
    f32x4*    pairs = (f32x4*)((char*)d_ws + (size_t)8 * N * 4 + DENSE_TOTAL * 8);  // +734 KB

    const int FB = (N + 511) / 512;
    const int PB = (N + 511) / 512;
    ngp_dehash<<<(DENSE_TOTAL + 255) / 256, 256, 0, stream>>>(tables, dense);
    {
        dim3 g((153 * 154 + 255) / 256, 4);   // max level count = L7
        ngp_dehash_pair<<<g, 256, 0, stream>>>(tables, pairs);
    }
    ngp_encode_fine<<<8 * FB, 256, 0, stream>>>(x, tables, feat, N);
    ngp_fused<<<PB, 512, 0, stream>>>(x, dense, pairs, feat,
                                      W0, b0, W1, b1, W2, b2, out, N);
}

// Round 8
// 260.391 us; speedup vs baseline: 1.0167x; 1.0167x over previous
//
#include <hip/hip_runtime.h>

#define LVLS  16
#define TSZ   524288u          // 2^19
#define TMASK (TSZ - 1u)
#define PRIME 2654435761u

// floor(16 * g^l), g = 128^(1/15) — matches np float64 floor then f32 cast
__constant__ float RES[LVLS] = {16.f, 22.f, 30.f, 42.f, 58.f, 80.f, 111.f, 153.f,
                                212.f, 294.f, 406.f, 561.f, 776.f, 1072.f, 1482.f, 2048.f};

typedef __bf16 bf16x8 __attribute__((ext_vector_type(8)));
typedef float  f32x4  __attribute__((ext_vector_type(4)));

union Frag {
    uint4          q;
    unsigned       u[4];
    unsigned short s[8];
    bf16x8         v;
};

static __device__ __forceinline__ unsigned short f2bf(float f) {
    unsigned u = __float_as_uint(f);
    u += 0x7FFFu + ((u >> 16) & 1u);          // RNE; inputs finite, non-NaN
    return (unsigned short)(u >> 16);
}
static __device__ __forceinline__ unsigned pack2(float a, float b) {
    return (unsigned)f2bf(a) | ((unsigned)f2bf(b) << 16);
}
// order LDS phases without cross-wave barriers (per-wave scratch only)
static __device__ __forceinline__ void lds_fence() {
    asm volatile("s_waitcnt lgkmcnt(0)" ::: "memory");
}

// Shared per-level encode math (identical FP sequence everywhere).
static __device__ __forceinline__ unsigned encode_level(
    const float2 xy, const float res, const float* __restrict__ tbf)
{
    const float sx = xy.x * res, sy = xy.y * res;
    const float fx = floorf(sx),  fy = floorf(sy);
    const float ux = sx - fx,     uy = sy - fy;
    const unsigned ix = (unsigned)(int)fx, iy = (unsigned)(int)fy;
    const unsigned hy0 = iy * PRIME, hy1 = (iy + 1u) * PRIME;
    const unsigned i00 = (ix ^ hy0) & TMASK;
    const unsigned i01 = (ix ^ hy1) & TMASK;
    float2 f00, f10, f01, f11;
    if (!(ix & 1u)) {
        // ix even -> i10 = i00^1, i11 = i01^1: each y-row's two corners are an
        // aligned 16 B pair -> one dwordx4 each (2 transactions, no extra bytes).
        const f32x4 a = *(const f32x4*)(tbf + 2u * (i00 & ~1u));
        const f32x4 b = *(const f32x4*)(tbf + 2u * (i01 & ~1u));
        const bool s0 = (i00 & 1u) != 0u;
        const bool s1 = (i01 & 1u) != 0u;
        f00 = s0 ? make_float2(a[2], a[3]) : make_float2(a[0], a[1]);
        f10 = s0 ? make_float2(a[0], a[1]) : make_float2(a[2], a[3]);
        f01 = s1 ? make_float2(b[2], b[3]) : make_float2(b[0], b[1]);
        f11 = s1 ? make_float2(b[0], b[1]) : make_float2(b[2], b[3]);
    } else {
        const unsigned i10 = ((ix + 1u) ^ hy0) & TMASK;
        const unsigned i11 = ((ix + 1u) ^ hy1) & TMASK;
        const float2* tb2 = (const float2*)tbf;
        f00 = tb2[i00]; f10 = tb2[i10];
        f01 = tb2[i01]; f11 = tb2[i11];
    }
    const float w00 = (1.f - ux) * (1.f - uy);
    const float w10 = ux * (1.f - uy);
    const float w01 = (1.f - ux) * uy;
    const float w11 = ux * uy;
    const float e0 = w00*f00.x + w10*f10.x + w01*f01.x + w11*f11.x;
    const float e1 = w00*f00.y + w10*f10.y + w01*f01.y + w11*f11.y;
    return pack2(e0, e1);
}

// Dense (de-hashed) coarse-table geometry, levels 0..3 (LDS-staged in K2).
// W = res+1 vertices per side: {17,23,31,43} -> 289,529,961,1849 entries,
// offsets {0,289,818,1779}, total 3628 entries = 29 KB of float2.
#define DENSE_TOTAL 3628

// ============ K0: de-hash L0-3 into dense [iy][ix] layout ============
// Values are exact copies of tables[l][hash(ix,iy)] -> numerics unchanged.
__global__ __launch_bounds__(256) void ngp_dehash(
    const float* __restrict__ tables, float2* __restrict__ dense)
{
    const int e = blockIdx.x * 256 + (int)threadIdx.x;
    if (e >= DENSE_TOTAL) return;
    int l, base;
    if      (e >= 1779) { l = 3; base = 1779; }
    else if (e >=  818) { l = 2; base =  818; }
    else if (e >=  289) { l = 1; base =  289; }
    else                { l = 0; base =    0; }
    const int Wd = (l == 0) ? 17 : (l == 1) ? 23 : (l == 2) ? 31 : 43;
    const int r  = e - base;
    const unsigned iy = (unsigned)(r / Wd), ix = (unsigned)(r % Wd);
    const unsigned h = (ix ^ (iy * PRIME)) & TMASK;
    dense[e] = ((const float2*)(tables + (size_t)l * (TSZ * 2u)))[h];
}

// ============ K1: fine levels 8..15, XCD-affine ============
// blockIdx%8 == XCD id (round-robin dispatch): level 8+k runs only on XCD k,
// its table stays L2-resident. AT THE WALL: ~3M random lines per hashed-level
// XCD in ~217K cycles = ~13.9 lines/cy/XCD ~= 87% of L2 random service rate.
// Verified insensitive to per-thread ILP (2pt/thread: null, round 7) and to
// occupancy; hashed levels (res^2 > T) irreducibly need ~3 lines/point-level.
__global__ __launch_bounds__(256) void ngp_encode_fine(
    const float* __restrict__ x, const float* __restrict__ tables,
    unsigned* __restrict__ feat, int N)
{
    const int g = blockIdx.x;
    const int r = g & 7;              // XCD id
    const int l = 8 + r;              // fine level pinned to this XCD
    const int n = (g >> 3) * 256 + (int)threadIdx.x;
    if (n >= N) return;
    const float2 xy = ((const float2*)x)[n];
    const float* tbf = tables + (size_t)l * (TSZ * 2u);
    feat[(size_t)r * N + n] = encode_level(xy, RES[l], tbf);   // coalesced
}

// ============ K2: coarse levels 0..7 + feat + MLP ============
// L0-3 corners from the LDS-staged dense table (no TA transactions, no hash);
// L4-7 gather from L2-resident hashed tables (408 KB, resident on every XCD).
// Block = 512 threads = 8 waves = 512 points; each wave runs the MFMA MLP on
// its 64 points (4 tiles of 16). A-frag quads 0-1 (levels 0-7) come from LDS
// sfeat; quads 2-3 (levels 8-15) stream coalesced from K1's feat.
//
// LDS phases (region after sfeat is time-shared):
//   phase A (stage+preload+encode): sB0 4K | sB1 8K | sdense 29K  = 41.3 KB
//   phase B (MLP):                  hscr 18.4 KB (aliases region base)
// syncs: [stage sB+sdense] S1 [preload B->regs; encode] S2 [MLP].
// B-frag preload moved BEFORE encode (round 8): its ds_read latency hides
// under encode issue, and S2 alone suffices before hscr aliasing (every
// wave's sB reads finished pre-encode). One barrier fewer than round 6.
//
// launch_bounds min-waves/EU MUST stay at 4 (round-2: asking 6 spilled the
// persistent B-frags to scratch, WRITE_SIZE 12->197 MB, 183->330 us).
//
// Layouts (m89/m120-verified): A[m=lane&15][k=quad*8+j], B[k=quad*8+j][n=lane&15],
// C/D col=lane&15 row=quad*4+reg.
#define CLVL 8
#define SFEAT_BYTES (8 * CLVL * 64 * 4)            // 16384
#define SB0_BYTES   (4 * 64 * 16)                  // 4096
#define SB1_BYTES   (8 * 64 * 16)                  // 8192
#define SDENSE_BYTES (DENSE_TOTAL * 8)             // 29024
#define REGION_BYTES (SB0_BYTES + SB1_BYTES + SDENSE_BYTES)   // 41312

__global__ __launch_bounds__(512, 4) void ngp_fused(
    const float* __restrict__ x, const float* __restrict__ tables,
    const float2* __restrict__ dense_g,
    const unsigned* __restrict__ feat,
    const float* __restrict__ W0, const float* __restrict__ b0,
    const float* __restrict__ W1, const float* __restrict__ b1,
    const float* __restrict__ W2, const float* __restrict__ b2,
    float* __restrict__ out, int N)
{
    __shared__ __align__(16) unsigned char smem[SFEAT_BYTES + REGION_BYTES];  // 57.7 KB
    // sfeat[w][lvl][col]: col XOR-swizzled by (lvl>>2)&1 so the A0 read
    // (2 coarse quads at same 16-col window) spreads across banks.
    unsigned* sfeat = (unsigned*)smem;                                   // [8][8][64]
    uint4*    sB0   = (uint4*)(smem + SFEAT_BYTES);                      // [4*64]
    uint4*    sB1   = (uint4*)(smem + SFEAT_BYTES + SB0_BYTES);          // [8*64]
    float2*   sdense = (float2*)(smem + SFEAT_BYTES + SB0_BYTES + SB1_BYTES);
    unsigned short (*hscr)[16][72] =
        (unsigned short (*)[16][72])(smem + SFEAT_BYTES);                // phase-B alias

    const int tid  = threadIdx.x;
    const int lane = tid & 63;
    const int w    = tid >> 6;       // wave 0..7
    const int c    = lane & 15;
    const int quad = lane >> 4;

    // ---- stage B fragments (bf16, B-operand layout) + dense tables ----
    {
        const int f = w;             // 0..7
        if (f < 4) {
            Frag t0;
            #pragma unroll
            for (int j = 0; j < 8; ++j)
                t0.s[j] = f2bf(W0[(quad * 8 + j) * 64 + f * 16 + c]);
            sB0[f * 64 + lane] = t0.q;
        }
        {
            const int kt = f >> 2, tt = f & 3;
            Frag t1;
            #pragma unroll
            for (int j = 0; j < 8; ++j)
                t1.s[j] = f2bf(W1[(kt * 32 + quad * 8 + j) * 64 + tt * 16 + c]);
            sB1[f * 64 + lane] = t1.q;
        }
        for (int e = tid; e < DENSE_TOTAL; e += 512)
            sdense[e] = dense_g[e];            // coalesced, L2/LLC-hit
    }
    __syncthreads();   // S1: sdense + sB visible

    // ---- preload B frags + biases to registers (before encode: latency
    // hides under encode issue; frees the need for a post-encode barrier) ----
    Frag B0f[4], B1f[8], B2f[2];
    #pragma unroll
    for (int t = 0; t < 4; ++t) B0f[t].q = sB0[t * 64 + lane];
    #pragma unroll
    for (int f = 0; f < 8; ++f) B1f[f].q = sB1[f * 64 + lane];
    #pragma unroll
    for (int f = 0; f < 2; ++f) {
        #pragma unroll
        for (int j = 0; j < 8; ++j) {
            const float v = (c < 3) ? W2[(f * 32 + quad * 8 + j) * 3 + c] : 0.f;
            B2f[f].s[j] = f2bf(v);
        }
    }
    float bias0[4], bias1[4];
    #pragma unroll
    for (int t = 0; t < 4; ++t) { bias0[t] = b0[t * 16 + c]; bias1[t] = b1[t * 16 + c]; }
    const float bias2 = (c < 3) ? b2[c] : 0.f;

    // ---- encode coarse levels 0..7 for this thread's point -> sfeat ----
    const int n = blockIdx.x * 512 + tid;
    if (n < N) {
        const float2 xy = ((const float2*)x)[n];
        // L0-3: dense LDS lookup (no hash, no vector-memory transactions)
        #pragma unroll
        for (int l = 0; l < 4; ++l) {
            const int off = (l == 0) ? 0 : (l == 1) ? 289 : (l == 2) ? 818 : 1779;
            const int Wd  = (l == 0) ? 17 : (l == 1) ? 23 : (l == 2) ? 31 : 43;
            const float res = RES[l];
            const float sx = xy.x * res, sy = xy.y * res;
            const float fx = floorf(sx),  fy = floorf(sy);
            const float ux = sx - fx,     uy = sy - fy;
            const int ix = (int)fx, iy = (int)fy;
            const int b = off + iy * Wd + ix;
            const float2 f00 = sdense[b],      f10 = sdense[b + 1];
            const float2 f01 = sdense[b + Wd], f11 = sdense[b + Wd + 1];
            const float w00 = (1.f - ux) * (1.f - uy);
            const float w10 = ux * (1.f - uy);
            const float w01 = (1.f - ux) * uy;
            const float w11 = ux * uy;
            const float e0 = w00*f00.x + w10*f10.x + w01*f01.x + w11*f11.x;
            const float e1 = w00*f00.y + w10*f10.y + w01*f01.y + w11*f11.y;
            sfeat[(w * CLVL + l) * 64 + (lane ^ (((l >> 2) & 1) << 4))] = pack2(e0, e1);
        }
        // L4-7: gather from L2-resident tables
        #pragma unroll 2
        for (int l = 4; l < CLVL; ++l) {
            const float* tbf = tables + (size_t)l * (TSZ * 2u);
            const unsigned p = encode_level(xy, RES[l], tbf);
            sfeat[(w * CLVL + l) * 64 + (lane ^ (((l >> 2) & 1) << 4))] = p;
        }
    }
    __syncthreads();   // S2: sfeat ready; sdense/sB dead -> hscr may alias

    // ---- 4 tiles of 16 points per wave ----
    #pragma unroll 1
    for (int it = 0; it < 4; ++it) {
        const int n0 = blockIdx.x * 512 + w * 64 + it * 16;

        // A0: dword i = levels quad*4+i -> k = quad*8+2i,2i+1
        // quads 0-1: coarse from sfeat (read swizzle ((quad*4+i)>>2)&1 == quad);
        // quads 2-3: fine from feat (coalesced 16x4B per (quad,i) group).
        Frag a0;
        if (quad < 2) {
            #pragma unroll
            for (int i = 0; i < 4; ++i)
                a0.u[i] = sfeat[(w * CLVL + quad * 4 + i) * 64 + ((it * 16 + c) ^ (quad << 4))];
        } else {
            #pragma unroll
            for (int i = 0; i < 4; ++i)
                a0.u[i] = feat[(size_t)((quad - 2) * 4 + i) * N + n0 + c];
        }

        f32x4 acc0[4];
        #pragma unroll
        for (int t = 0; t < 4; ++t) {
            f32x4 cin = {bias0[t], bias0[t], bias0[t], bias0[t]};
            acc0[t] = __builtin_amdgcn_mfma_f32_16x16x32_bf16(a0.v, B0f[t].v, cin, 0, 0, 0);
        }

        // h1 = relu(acc0) -> LDS scratch [point][neuron]
        lds_fence();
        #pragma unroll
        for (int t = 0; t < 4; ++t)
            #pragma unroll
            for (int rr = 0; rr < 4; ++rr)
                hscr[w][quad * 4 + rr][t * 16 + c] = f2bf(fmaxf(acc0[t][rr], 0.f));

        lds_fence();
        Frag a1[2];
        #pragma unroll
        for (int kt = 0; kt < 2; ++kt)
            a1[kt].q = *(const uint4*)&hscr[w][c][kt * 32 + quad * 8];

        f32x4 acc1[4];
        #pragma unroll
        for (int t = 0; t < 4; ++t) {
            f32x4 cin = {bias1[t], bias1[t], bias1[t], bias1[t]};
            cin = __builtin_amdgcn_mfma_f32_16x16x32_bf16(a1[0].v, B1f[t].v, cin, 0, 0, 0);
            acc1[t] = __builtin_amdgcn_mfma_f32_16x16x32_bf16(a1[1].v, B1f[4 + t].v, cin, 0, 0, 0);
        }

        // h2 = relu(acc1) -> LDS scratch
        lds_fence();
        #pragma unroll
        for (int t = 0; t < 4; ++t)
            #pragma unroll
            for (int rr = 0; rr < 4; ++rr)
                hscr[w][quad * 4 + rr][t * 16 + c] = f2bf(fmaxf(acc1[t][rr], 0.f));

        lds_fence();
        Frag a2[2];
        #pragma unroll
        for (int kt = 0; kt < 2; ++kt)
            a2[kt].q = *(const uint4*)&hscr[w][c][kt * 32 + quad * 8];

        f32x4 cin2 = {bias2, bias2, bias2, bias2};
        cin2 = __builtin_amdgcn_mfma_f32_16x16x32_bf16(a2[0].v, B2f[0].v, cin2, 0, 0, 0);
        f32x4 acc2 = __builtin_amdgcn_mfma_f32_16x16x32_bf16(a2[1].v, B2f[1].v, cin2, 0, 0, 0);

        // sigmoid + store: lane col c<3, rows quad*4+rr
        if (c < 3) {
            #pragma unroll
            for (int rr = 0; rr < 4; ++rr) {
                if (n0 + quad * 4 + rr < N) {
                    const float s = 1.f / (1.f + __expf(-acc2[rr]));
                    out[(size_t)(n0 + quad * 4 + rr) * 3 + c] = s;
                }
            }
        }
    }
}

extern "C" void kernel_launch(void* const* d_in, const int* in_sizes, int n_in,
                              void* d_out, int out_size, void* d_ws, size_t ws_size,
                              hipStream_t stream) {
    const float* x      = (const float*)d_in[0];
    const float* tables = (const float*)d_in[1];
    const float* W0     = (const float*)d_in[2];
    const float* b0     = (const float*)d_in[3];
    const float* W1     = (const float*)d_in[4];
    const float* b1     = (const float*)d_in[5];
    const float* W2     = (const float*)d_in[6];
    const float* b2     = (const float*)d_in[7];
    float* out = (float*)d_out;
    (void)ws_size; (void)n_in; (void)out_size;

    const int N  = in_sizes[0] / 2;
    unsigned* feat  = (unsigned*)d_ws;                               // 8*N*4 = 32 MB
    float2*   dense = (float2*)((char*)d_ws + (size_t)8 * N * 4);    // +29 KB

    const int FB = (N + 255) / 256;
    const int PB = (N + 511) / 512;
    ngp_dehash<<<(DENSE_TOTAL + 255) / 256, 256, 0, stream>>>(tables, dense);
    ngp_encode_fine<<<8 * FB, 256, 0, stream>>>(x, tables, feat, N);
    ngp_fused<<<PB, 512, 0, stream>>>(x, tables, dense, feat,
                                      W0, b0, W1, b1, W2, b2, out, N);
}